// Round 7
// baseline (139.024 us; speedup 1.0000x reference)
//
#include <hip/hip_runtime.h>

// SVF cascade frequency response on MI355X (gfx950) — R6.
//
// H(x) = (1+1j) * prod_k (b0+b1/x+b2/x^2)/(a0+a1/x+a2/x^2)
//      = (1+1j) * prod_k (b0*x^2+b1*x+b2)/(a0*x^2+a1*x+a2)    <- no xinv
//
// Established facts:
//  - Output layout PLANAR (R4): out[0..n-1]=Re H, out[n..2n-1]=Im H,
//    out_size >= 2n (R4's 2n-gated fast path executed).
//  - Reference is float32-computed numpy (R4's f64 kernel scored 3.8e-6,
//    not ~1e-12 -> that residue is the ref's own f32 noise). Threshold
//    1.074e-4 = 2% of ref absmax; f64 compute gives ~28x margin.
//  - Aborts (R0, R5) correlate with unguarded stores; guarded versions
//    (R1, R4) always ran. No provable OOB, but guards are free -> keep.
//
// R6 = sequential per-section f64 complex division (numpy op order, no
// deferred grouping -> output insensitive to evaluation order) + R4-style
// full store guarding. Single f64->f32 rounding at the store.

#define NSEC  64
#define BLOCK 256
#define MPT   4    // samples per thread (f64 regs: 2 VGPRs each)

__global__ __launch_bounds__(BLOCK) void svf_f64_v6(
    const float* __restrict__ xr_g, const float* __restrict__ xi_g,
    const float* __restrict__ f_g,  const float* __restrict__ R_g,
    const float* __restrict__ lp_g, const float* __restrict__ bp_g,
    const float* __restrict__ hp_g,
    float* __restrict__ out, int n, long long cap_floats)
{
    __shared__ double sb0[NSEC], sb1[NSEC], sb2[NSEC];
    __shared__ double sa0[NSEC], sa1[NSEC], sa2[NSEC];

    const int t = threadIdx.x;
    if (t < NSEC) {
        const double fk = (double)f_g[t],  Rk = (double)R_g[t];
        const double lp = (double)lp_g[t], bp = (double)bp_g[t];
        const double hp = (double)hp_g[t];
        const double f2  = fk * fk;
        const double fbp = fk * bp;
        const double flp = f2 * lp;
        const double rf2 = 2.0 * Rk * fk;
        sb0[t] = flp + fbp + hp;
        sb1[t] = 2.0 * flp - 2.0 * hp;
        sb2[t] = flp - fbp + hp;
        sa0[t] = f2 + rf2 + 1.0;
        sa1[t] = 2.0 * f2 - 2.0;
        sa2[t] = f2 - rf2 + 1.0;
    }
    __syncthreads();

    const long long base = (long long)(blockIdx.x * BLOCK + t) * MPT;

    double Xr[MPT], Xi[MPT], X2r[MPT], X2i[MPT], Hr[MPT], Hi[MPT];

    if (base + MPT <= (long long)n) {
        const float4 a = *reinterpret_cast<const float4*>(xr_g + base);
        const float4 b = *reinterpret_cast<const float4*>(xi_g + base);
        Xr[0] = (double)a.x; Xr[1] = (double)a.y;
        Xr[2] = (double)a.z; Xr[3] = (double)a.w;
        Xi[0] = (double)b.x; Xi[1] = (double)b.y;
        Xi[2] = (double)b.z; Xi[3] = (double)b.w;
    } else {
        for (int m = 0; m < MPT; ++m) {
            const long long idx = base + m;
            const bool ok = idx < (long long)n;
            Xr[m] = ok ? (double)xr_g[idx] : 1.0;
            Xi[m] = ok ? (double)xi_g[idx] : 0.0;
        }
    }

    #pragma unroll
    for (int m = 0; m < MPT; ++m) {
        X2r[m] = fma(Xr[m], Xr[m], -(Xi[m] * Xi[m]));   // Re(x^2)
        X2i[m] = 2.0 * Xr[m] * Xi[m];                   // Im(x^2)
        Hr[m] = 1.0;   // H starts at (1 + 1j)
        Hi[m] = 1.0;
    }

    #pragma unroll 2
    for (int k = 0; k < NSEC; ++k) {
        const double b0 = sb0[k], b1 = sb1[k], b2 = sb2[k];
        const double a0 = sa0[k], a1 = sa1[k], a2 = sa2[k];
        #pragma unroll
        for (int m = 0; m < MPT; ++m) {
            // num = b0*x^2 + b1*x + b2   (real coefs, complex x)
            const double nr = fma(b0, X2r[m], fma(b1, Xr[m], b2));
            const double ni = fma(b0, X2i[m], b1 * Xi[m]);
            // den = a0*x^2 + a1*x + a2
            const double dr = fma(a0, X2r[m], fma(a1, Xr[m], a2));
            const double di = fma(a0, X2i[m], a1 * Xi[m]);
            // ratio = num/den, divided PER SECTION (numpy op order)
            const double d2  = fma(dr, dr, di * di);
            const double inv = 1.0 / d2;                 // exact IEEE f64 div
            const double rr  = fma(nr, dr,   ni * di) * inv;
            const double ri  = fma(ni, dr, -(nr * di)) * inv;
            // H *= ratio
            const double hr = fma(Hr[m], rr, -(Hi[m] * ri));
            const double hi = fma(Hr[m], ri,   Hi[m] * rr);
            Hr[m] = hr; Hi[m] = hi;
        }
    }

    // PLANAR output: out[0..n-1] = Re H, out[n..2n-1] = Im H.
    // Single f64->f32 rounding here. EVERY store guarded by cap_floats
    // (aborts R0/R5 correlate with unguarded stores; guards are free).
    const long long imag_off = (long long)n;
    if (base + MPT <= (long long)n && 2LL * (long long)n <= cap_floats) {
        float4 vr, vi;
        vr.x = (float)Hr[0]; vr.y = (float)Hr[1];
        vr.z = (float)Hr[2]; vr.w = (float)Hr[3];
        vi.x = (float)Hi[0]; vi.y = (float)Hi[1];
        vi.z = (float)Hi[2]; vi.w = (float)Hi[3];
        *reinterpret_cast<float4*>(out + base)            = vr;
        *reinterpret_cast<float4*>(out + imag_off + base) = vi;
    } else {
        for (int m = 0; m < MPT; ++m) {
            const long long idx = base + m;
            if (idx < (long long)n) {
                if (idx + 1 <= cap_floats) out[idx] = (float)Hr[m];
                const long long oi = imag_off + idx;
                if (oi + 1 <= cap_floats) out[oi] = (float)Hi[m];
            }
        }
    }
}

extern "C" void kernel_launch(void* const* d_in, const int* in_sizes, int n_in,
                              void* d_out, int out_size, void* d_ws, size_t ws_size,
                              hipStream_t stream) {
    const float* xr = (const float*)d_in[0];
    const float* xi = (const float*)d_in[1];
    const float* f  = (const float*)d_in[2];
    const float* R  = (const float*)d_in[3];
    const float* lp = (const float*)d_in[4];
    const float* bp = (const float*)d_in[5];
    const float* hp = (const float*)d_in[6];
    float* out = (float*)d_out;

    const int n = in_sizes[0];  // 1048576
    long long cap = (long long)out_size;
    if (cap > 2LL * (long long)n) cap = 2LL * (long long)n;

    const int grid = (n + BLOCK * MPT - 1) / (BLOCK * MPT);  // 1024
    svf_f64_v6<<<grid, BLOCK, 0, stream>>>(xr, xi, f, R, lp, bp, hp, out, n, cap);
}

// Round 8
// 106.682 us; speedup vs baseline: 1.3032x; 1.3032x over previous
//
#include <hip/hip_runtime.h>

// SVF cascade frequency response on MI355X (gfx950) — R7.
//
// H(x) = (1+1j) * prod_k (b0+b1/x+b2/x^2)/(a0+a1/x+a2/x^2)
//      = (1+1j) * prod_k (b0*x^2+b1*x+b2)/(a0*x^2+a1*x+a2)
//
// Established (R4/R6): PLANAR output [Re H | Im H], out_size >= 2n; np ref
// is f32-computed (absmax residue 3.8e-6 is the REF's noise; threshold
// 1.074e-4); f64 internal compute passes with 28x margin. R6 measured:
// 84.5 us/dispatch, VALUBusy 74%, f64-VALU-throughput-bound.
//
// R7 op-count attack (2x fewer f64 slots/section):
//  1) v_rcp_f64 + 2 Newton (5 ops) replaces IEEE divide (~13 ops).
//  2) Adjacent sections fused into real-coefficient QUARTIC rationals:
//     (b0x^2+b1x+b2)(b0'x^2+b1'x+b2') = c0x^4+c1x^3+c2x^2+c3x+c4, real ci,
//     precomputed in LDS. Powers x..x^4 precomputed per sample, so a
//     quartic costs 8 fma (same as two quadratics) but the per-stage
//     overhead (|den|^2, complex mults, rcp, H-update) is paid 32x not 64x.
//     Stage rel-error <= ~2e-5 worst case -> final abs <= ~1e-7, negligible.
// Expected: 84.5 -> ~45-58 us/dispatch.

#define NSEC  64
#define NPAIR 32
#define BLOCK 256
#define MPT   4    // samples per thread

__device__ __forceinline__ double rcp_f64_full(double a) {
    double y = __builtin_amdgcn_rcp(a);        // v_rcp_f64, ~1e-8 rel
    y = fma(fma(-a, y, 1.0), y, y);            // Newton -> ~1e-16
    y = fma(fma(-a, y, 1.0), y, y);            // Newton -> ~0.5 ulp
    return y;
}

__global__ __launch_bounds__(BLOCK) void svf_f64_v7(
    const float* __restrict__ xr_g, const float* __restrict__ xi_g,
    const float* __restrict__ f_g,  const float* __restrict__ R_g,
    const float* __restrict__ lp_g, const float* __restrict__ bp_g,
    const float* __restrict__ hp_g,
    float* __restrict__ out, int n, long long cap_floats)
{
    __shared__ double sn[NPAIR][5];   // numerator quartic c0..c4 per pair
    __shared__ double sd[NPAIR][5];   // denominator quartic c0..c4 per pair

    const int t = threadIdx.x;
    if (t < NPAIR) {
        const int k0 = 2 * t, k1 = 2 * t + 1;
        // section k0 biquad coefs (x^2-multiplied form)
        double fk = (double)f_g[k0],  Rk = (double)R_g[k0];
        double lp = (double)lp_g[k0], bp = (double)bp_g[k0], hp = (double)hp_g[k0];
        double f2 = fk * fk, fbp = fk * bp, flp = f2 * lp, rf2 = 2.0 * Rk * fk;
        const double b0 = flp + fbp + hp, b1 = 2.0 * flp - 2.0 * hp, b2 = flp - fbp + hp;
        const double a0 = f2 + rf2 + 1.0, a1 = 2.0 * f2 - 2.0,       a2 = f2 - rf2 + 1.0;
        // section k1
        fk = (double)f_g[k1];  Rk = (double)R_g[k1];
        lp = (double)lp_g[k1]; bp = (double)bp_g[k1]; hp = (double)hp_g[k1];
        f2 = fk * fk; fbp = fk * bp; flp = f2 * lp; rf2 = 2.0 * Rk * fk;
        const double B0 = flp + fbp + hp, B1 = 2.0 * flp - 2.0 * hp, B2 = flp - fbp + hp;
        const double A0 = f2 + rf2 + 1.0, A1 = 2.0 * f2 - 2.0,       A2 = f2 - rf2 + 1.0;
        // quartic products (real coefficients)
        sn[t][0] = b0 * B0;
        sn[t][1] = b0 * B1 + b1 * B0;
        sn[t][2] = b0 * B2 + b1 * B1 + b2 * B0;
        sn[t][3] = b1 * B2 + b2 * B1;
        sn[t][4] = b2 * B2;
        sd[t][0] = a0 * A0;
        sd[t][1] = a0 * A1 + a1 * A0;
        sd[t][2] = a0 * A2 + a1 * A1 + a2 * A0;
        sd[t][3] = a1 * A2 + a2 * A1;
        sd[t][4] = a2 * A2;
    }
    __syncthreads();

    const long long base = (long long)(blockIdx.x * BLOCK + t) * MPT;

    double Xr[MPT], Xi[MPT];
    double X2r[MPT], X2i[MPT], X3r[MPT], X3i[MPT], X4r[MPT], X4i[MPT];
    double Hr[MPT], Hi[MPT];

    if (base + MPT <= (long long)n) {
        const float4 a = *reinterpret_cast<const float4*>(xr_g + base);
        const float4 b = *reinterpret_cast<const float4*>(xi_g + base);
        Xr[0] = (double)a.x; Xr[1] = (double)a.y;
        Xr[2] = (double)a.z; Xr[3] = (double)a.w;
        Xi[0] = (double)b.x; Xi[1] = (double)b.y;
        Xi[2] = (double)b.z; Xi[3] = (double)b.w;
    } else {
        for (int m = 0; m < MPT; ++m) {
            const long long idx = base + m;
            const bool ok = idx < (long long)n;
            Xr[m] = ok ? (double)xr_g[idx] : 1.0;
            Xi[m] = ok ? (double)xi_g[idx] : 0.0;
        }
    }

    #pragma unroll
    for (int m = 0; m < MPT; ++m) {
        X2r[m] = fma(Xr[m],  Xr[m],  -(Xi[m]  * Xi[m]));   // x^2
        X2i[m] = 2.0 * Xr[m] * Xi[m];
        X3r[m] = fma(X2r[m], Xr[m],  -(X2i[m] * Xi[m]));   // x^3
        X3i[m] = fma(X2r[m], Xi[m],    X2i[m] * Xr[m]);
        X4r[m] = fma(X2r[m], X2r[m], -(X2i[m] * X2i[m]));  // x^4
        X4i[m] = 2.0 * X2r[m] * X2i[m];
        Hr[m] = 1.0;   // H starts at (1 + 1j)
        Hi[m] = 1.0;
    }

    #pragma unroll 2
    for (int p = 0; p < NPAIR; ++p) {
        const double c0 = sn[p][0], c1 = sn[p][1], c2 = sn[p][2];
        const double c3 = sn[p][3], c4 = sn[p][4];
        const double d0 = sd[p][0], d1 = sd[p][1], d2c = sd[p][2];
        const double d3 = sd[p][3], d4 = sd[p][4];
        #pragma unroll
        for (int m = 0; m < MPT; ++m) {
            // num quartic (real coefs, complex powers precomputed): 8 fma
            const double nr = fma(c0, X4r[m], fma(c1, X3r[m],
                               fma(c2, X2r[m], fma(c3, Xr[m], c4))));
            const double ni = fma(c0, X4i[m], fma(c1, X3i[m],
                               fma(c2, X2i[m], c3 * Xi[m])));
            // den quartic: 8 fma
            const double dr = fma(d0, X4r[m], fma(d1, X3r[m],
                               fma(d2c, X2r[m], fma(d3, Xr[m], d4))));
            const double di = fma(d0, X4i[m], fma(d1, X3i[m],
                               fma(d2c, X2i[m], d3 * Xi[m])));
            // ratio = num * conj(den) / |den|^2 (per-stage division)
            const double dd  = fma(dr, dr, di * di);
            const double inv = rcp_f64_full(dd);
            const double rr  = fma(nr, dr,   ni * di) * inv;
            const double ri  = fma(ni, dr, -(nr * di)) * inv;
            // H *= ratio
            const double hr = fma(Hr[m], rr, -(Hi[m] * ri));
            const double hi = fma(Hr[m], ri,   Hi[m] * rr);
            Hr[m] = hr; Hi[m] = hi;
        }
    }

    // PLANAR output: out[0..n-1] = Re H, out[n..2n-1] = Im H.
    // Single f64->f32 rounding; every store guarded by cap_floats.
    const long long imag_off = (long long)n;
    if (base + MPT <= (long long)n && 2LL * (long long)n <= cap_floats) {
        float4 vr, vi;
        vr.x = (float)Hr[0]; vr.y = (float)Hr[1];
        vr.z = (float)Hr[2]; vr.w = (float)Hr[3];
        vi.x = (float)Hi[0]; vi.y = (float)Hi[1];
        vi.z = (float)Hi[2]; vi.w = (float)Hi[3];
        *reinterpret_cast<float4*>(out + base)            = vr;
        *reinterpret_cast<float4*>(out + imag_off + base) = vi;
    } else {
        for (int m = 0; m < MPT; ++m) {
            const long long idx = base + m;
            if (idx < (long long)n) {
                if (idx + 1 <= cap_floats) out[idx] = (float)Hr[m];
                const long long oi = imag_off + idx;
                if (oi + 1 <= cap_floats) out[oi] = (float)Hi[m];
            }
        }
    }
}

extern "C" void kernel_launch(void* const* d_in, const int* in_sizes, int n_in,
                              void* d_out, int out_size, void* d_ws, size_t ws_size,
                              hipStream_t stream) {
    const float* xr = (const float*)d_in[0];
    const float* xi = (const float*)d_in[1];
    const float* f  = (const float*)d_in[2];
    const float* R  = (const float*)d_in[3];
    const float* lp = (const float*)d_in[4];
    const float* bp = (const float*)d_in[5];
    const float* hp = (const float*)d_in[6];
    float* out = (float*)d_out;

    const int n = in_sizes[0];  // 1048576
    long long cap = (long long)out_size;
    if (cap > 2LL * (long long)n) cap = 2LL * (long long)n;

    const int grid = (n + BLOCK * MPT - 1) / (BLOCK * MPT);  // 1024
    svf_f64_v7<<<grid, BLOCK, 0, stream>>>(xr, xi, f, R, lp, bp, hp, out, n, cap);
}

// Round 9
// 103.531 us; speedup vs baseline: 1.3428x; 1.0304x over previous
//
#include <hip/hip_runtime.h>

// SVF cascade frequency response on MI355X (gfx950) — R8.
//
// H(x) = (1+1j) * prod_k (b0+b1/x+b2/x^2)/(a0+a1/x+a2/x^2)
//      = (1+1j) * prod_k (b0*x^2+b1*x+b2)/(a0*x^2+a1*x+a2)
//
// Established: PLANAR output [Re H | Im H]; np ref is f32-computed (3.8e-6
// residue is the ref's own noise); f64 internal compute, per-stage division
// (two green runs — do not reopen deferred division); quartic pair-fusion
// with powers x..x^4 precomputed (R7: 48.6 us, VALUBusy ~65%).
//
// R8 attack: TLP, not ops. 1024 blocks was exactly 4 blocks/CU resident and
// f64 chains stalled with no spare waves. MPT 4->2 keeps per-sample op order
// BIT-IDENTICAL but doubles the grid (2048 blocks) and cuts VGPRs ->
// ~6 blocks/CU resident. Plus rcp: 1 Newton step (seed 1e-8 -> 1e-16 ~ 1ulp)
// saves 2 ops/stage. Predicted 48.6 -> ~32-38 us dispatch.

#define NSEC  64
#define NPAIR 32
#define BLOCK 256
#define MPT   2    // samples per thread

__device__ __forceinline__ double rcp_f64_n1(double a) {
    double y = __builtin_amdgcn_rcp(a);        // v_rcp_f64, ~1e-8 rel
    y = fma(fma(-a, y, 1.0), y, y);            // 1 Newton -> ~1e-16 (~1 ulp)
    return y;
}

__global__ __launch_bounds__(BLOCK) void svf_f64_v8(
    const float* __restrict__ xr_g, const float* __restrict__ xi_g,
    const float* __restrict__ f_g,  const float* __restrict__ R_g,
    const float* __restrict__ lp_g, const float* __restrict__ bp_g,
    const float* __restrict__ hp_g,
    float* __restrict__ out, int n, long long cap_floats)
{
    __shared__ double sn[NPAIR][5];   // numerator quartic c0..c4 per pair
    __shared__ double sd[NPAIR][5];   // denominator quartic c0..c4 per pair

    const int t = threadIdx.x;
    if (t < NPAIR) {
        const int k0 = 2 * t, k1 = 2 * t + 1;
        double fk = (double)f_g[k0],  Rk = (double)R_g[k0];
        double lp = (double)lp_g[k0], bp = (double)bp_g[k0], hp = (double)hp_g[k0];
        double f2 = fk * fk, fbp = fk * bp, flp = f2 * lp, rf2 = 2.0 * Rk * fk;
        const double b0 = flp + fbp + hp, b1 = 2.0 * flp - 2.0 * hp, b2 = flp - fbp + hp;
        const double a0 = f2 + rf2 + 1.0, a1 = 2.0 * f2 - 2.0,       a2 = f2 - rf2 + 1.0;
        fk = (double)f_g[k1];  Rk = (double)R_g[k1];
        lp = (double)lp_g[k1]; bp = (double)bp_g[k1]; hp = (double)hp_g[k1];
        f2 = fk * fk; fbp = fk * bp; flp = f2 * lp; rf2 = 2.0 * Rk * fk;
        const double B0 = flp + fbp + hp, B1 = 2.0 * flp - 2.0 * hp, B2 = flp - fbp + hp;
        const double A0 = f2 + rf2 + 1.0, A1 = 2.0 * f2 - 2.0,       A2 = f2 - rf2 + 1.0;
        sn[t][0] = b0 * B0;
        sn[t][1] = b0 * B1 + b1 * B0;
        sn[t][2] = b0 * B2 + b1 * B1 + b2 * B0;
        sn[t][3] = b1 * B2 + b2 * B1;
        sn[t][4] = b2 * B2;
        sd[t][0] = a0 * A0;
        sd[t][1] = a0 * A1 + a1 * A0;
        sd[t][2] = a0 * A2 + a1 * A1 + a2 * A0;
        sd[t][3] = a1 * A2 + a2 * A1;
        sd[t][4] = a2 * A2;
    }
    __syncthreads();

    const long long base = (long long)(blockIdx.x * BLOCK + t) * MPT;

    double Xr[MPT], Xi[MPT];
    double X2r[MPT], X2i[MPT], X3r[MPT], X3i[MPT], X4r[MPT], X4i[MPT];
    double Hr[MPT], Hi[MPT];

    if (base + MPT <= (long long)n) {
        const float2 a = *reinterpret_cast<const float2*>(xr_g + base);
        const float2 b = *reinterpret_cast<const float2*>(xi_g + base);
        Xr[0] = (double)a.x; Xr[1] = (double)a.y;
        Xi[0] = (double)b.x; Xi[1] = (double)b.y;
    } else {
        for (int m = 0; m < MPT; ++m) {
            const long long idx = base + m;
            const bool ok = idx < (long long)n;
            Xr[m] = ok ? (double)xr_g[idx] : 1.0;
            Xi[m] = ok ? (double)xi_g[idx] : 0.0;
        }
    }

    #pragma unroll
    for (int m = 0; m < MPT; ++m) {
        X2r[m] = fma(Xr[m],  Xr[m],  -(Xi[m]  * Xi[m]));   // x^2
        X2i[m] = 2.0 * Xr[m] * Xi[m];
        X3r[m] = fma(X2r[m], Xr[m],  -(X2i[m] * Xi[m]));   // x^3
        X3i[m] = fma(X2r[m], Xi[m],    X2i[m] * Xr[m]);
        X4r[m] = fma(X2r[m], X2r[m], -(X2i[m] * X2i[m]));  // x^4
        X4i[m] = 2.0 * X2r[m] * X2i[m];
        Hr[m] = 1.0;   // H starts at (1 + 1j)
        Hi[m] = 1.0;
    }

    #pragma unroll 2
    for (int p = 0; p < NPAIR; ++p) {
        const double c0 = sn[p][0], c1 = sn[p][1], c2 = sn[p][2];
        const double c3 = sn[p][3], c4 = sn[p][4];
        const double d0 = sd[p][0], d1 = sd[p][1], d2c = sd[p][2];
        const double d3 = sd[p][3], d4 = sd[p][4];
        #pragma unroll
        for (int m = 0; m < MPT; ++m) {
            // num quartic (real coefs, complex powers precomputed)
            const double nr = fma(c0, X4r[m], fma(c1, X3r[m],
                               fma(c2, X2r[m], fma(c3, Xr[m], c4))));
            const double ni = fma(c0, X4i[m], fma(c1, X3i[m],
                               fma(c2, X2i[m], c3 * Xi[m])));
            // den quartic
            const double dr = fma(d0, X4r[m], fma(d1, X3r[m],
                               fma(d2c, X2r[m], fma(d3, Xr[m], d4))));
            const double di = fma(d0, X4i[m], fma(d1, X3i[m],
                               fma(d2c, X2i[m], d3 * Xi[m])));
            // ratio = num * conj(den) / |den|^2 (per-stage division)
            const double dd  = fma(dr, dr, di * di);
            const double inv = rcp_f64_n1(dd);
            const double rr  = fma(nr, dr,   ni * di) * inv;
            const double ri  = fma(ni, dr, -(nr * di)) * inv;
            // H *= ratio
            const double hr = fma(Hr[m], rr, -(Hi[m] * ri));
            const double hi = fma(Hr[m], ri,   Hi[m] * rr);
            Hr[m] = hr; Hi[m] = hi;
        }
    }

    // PLANAR output: out[0..n-1] = Re H, out[n..2n-1] = Im H.
    // Single f64->f32 rounding; every store guarded by cap_floats.
    const long long imag_off = (long long)n;
    if (base + MPT <= (long long)n && 2LL * (long long)n <= cap_floats) {
        float2 vr, vi;
        vr.x = (float)Hr[0]; vr.y = (float)Hr[1];
        vi.x = (float)Hi[0]; vi.y = (float)Hi[1];
        *reinterpret_cast<float2*>(out + base)            = vr;
        *reinterpret_cast<float2*>(out + imag_off + base) = vi;
    } else {
        for (int m = 0; m < MPT; ++m) {
            const long long idx = base + m;
            if (idx < (long long)n) {
                if (idx + 1 <= cap_floats) out[idx] = (float)Hr[m];
                const long long oi = imag_off + idx;
                if (oi + 1 <= cap_floats) out[oi] = (float)Hi[m];
            }
        }
    }
}

extern "C" void kernel_launch(void* const* d_in, const int* in_sizes, int n_in,
                              void* d_out, int out_size, void* d_ws, size_t ws_size,
                              hipStream_t stream) {
    const float* xr = (const float*)d_in[0];
    const float* xi = (const float*)d_in[1];
    const float* f  = (const float*)d_in[2];
    const float* R  = (const float*)d_in[3];
    const float* lp = (const float*)d_in[4];
    const float* bp = (const float*)d_in[5];
    const float* hp = (const float*)d_in[6];
    float* out = (float*)d_out;

    const int n = in_sizes[0];  // 1048576
    long long cap = (long long)out_size;
    if (cap > 2LL * (long long)n) cap = 2LL * (long long)n;

    const int grid = (n + BLOCK * MPT - 1) / (BLOCK * MPT);  // 2048
    svf_f64_v8<<<grid, BLOCK, 0, stream>>>(xr, xi, f, R, lp, bp, hp, out, n, cap);
}